// Round 9
// baseline (5800.900 us; speedup 1.0000x reference)
//
#include <hip/hip_runtime.h>
#include <math.h>

// AVWDCRNN round 9 = round 8 with the k_a2 missing-brace compile fix.
// (all-f32, correct since r5; r7=1537us)
// Launch-count attack: fuse y-GEMM + per-node mm + GRU epilogue into ONE
// k_step kernel per half-step (gate/update) -> 2 launches/(l,t) instead of 4.
// x-part of y is step-invariant per layer: Y0X (l0, 2 cols) and batched
// Y1X (l1, 64 cols from cur0) precomputed for all t.

#define NF __restrict__
constexpr int N_ = 256, B_ = 8, T_ = 12, H_ = 64, E_ = 16;

__global__ void k_sentinel(float* NF out) { out[0] = 1.0e6f; }

// ---------------- adj = softmax(relu(ne ne^T), axis=1) ----------------
__global__ void k_adj(const float* NF ne, float* NF adj) {
    int n = blockIdx.x, m = threadIdx.x;
    __shared__ float en[E_];
    __shared__ float red[256];
    if (m < E_) en[m] = ne[n * E_ + m];
    __syncthreads();
    float s = 0.f;
#pragma unroll
    for (int d = 0; d < E_; d++) s += en[d] * ne[m * E_ + d];
    s = fmaxf(s, 0.f);
    red[m] = s; __syncthreads();
    for (int st = 128; st > 0; st >>= 1) { if (m < st) red[m] = fmaxf(red[m], red[m + st]); __syncthreads(); }
    float mx = red[0]; __syncthreads();
    float e = __expf(s - mx);
    red[m] = e; __syncthreads();
    for (int st = 128; st > 0; st >>= 1) { if (m < st) red[m] += red[m + st]; __syncthreads(); }
    adj[(size_t)n * N_ + m] = e / red[0];
}

// ------------- bias[n,o] = sum_d e[n,d] bp[d,o] -------------
template <int O>
__global__ void k_bias(const float* NF ne, const float* NF bp, float* NF Bout) {
    int n = blockIdx.x, o = threadIdx.x;
    float acc = 0.f;
#pragma unroll
    for (int d = 0; d < E_; d++) acc += ne[n * E_ + d] * bp[d * O + o];
    Bout[(size_t)n * O + o] = acc;
}

// ------------- W[n,j,o] = sum_d e[n,d] wp[d,j,o], float4 flat -------------
__global__ void k_wpool(const float* NF ne, const float* NF wp, float* NF W,
                        int I2, int O4, int total4) {
    int idx4 = blockIdx.x * 256 + threadIdx.x;
    if (idx4 >= total4) return;
    int o4 = idx4 % O4; int rem = idx4 / O4; int j = rem % I2; int n = rem / I2;
    const float* nrow = ne + n * E_;
    float ax = 0.f, ay = 0.f, az = 0.f, aw = 0.f;
#pragma unroll
    for (int d = 0; d < E_; d++) {
        float e = nrow[d];
        const float4 w = *(const float4*)&wp[(((size_t)d * I2 + j) * O4 + o4) * 4];
        ax = fmaf(e, w.x, ax); ay = fmaf(e, w.y, ay); az = fmaf(e, w.z, az); aw = fmaf(e, w.w, aw);
    }
    float4 r; r.x = ax; r.y = ay; r.z = az; r.w = aw;
    *(float4*)&W[(size_t)idx4 * 4] = r;
}

// ------------- E[tb,i,j] = exp(-L1(pa_i, pa_j)) ; tiled 64x64 -------------
__global__ __launch_bounds__(256) void k_sub_t(const float* NF pa, float* NF Ebuf) {
    int bx = blockIdx.x, tb = blockIdx.y;    // grid (16, 96)
    int it = bx & 3, jt = bx >> 2;
    int t = tb / B_, b = tb % B_;
    const float* p = pa + ((size_t)b * T_ + t) * N_ * H_;
    __shared__ float piT[64][64];
    __shared__ float pjT[64][64];
    int tid = threadIdx.x;
    int i0 = it * 64, j0 = jt * 64;
#pragma unroll
    for (int q = 0; q < 4; q++) {
        int idx = q * 256 + tid; int hq = idx & 15, i = idx >> 4;
        float4 v = *(const float4*)&p[(size_t)(i0 + i) * 64 + hq * 4];
        piT[hq * 4 + 0][i] = v.x; piT[hq * 4 + 1][i] = v.y; piT[hq * 4 + 2][i] = v.z; piT[hq * 4 + 3][i] = v.w;
        float4 w = *(const float4*)&p[(size_t)(j0 + i) * 64 + hq * 4];
        pjT[hq * 4 + 0][i] = w.x; pjT[hq * 4 + 1][i] = w.y; pjT[hq * 4 + 2][i] = w.z; pjT[hq * 4 + 3][i] = w.w;
    }
    __syncthreads();
    int jg = tid & 15, ig = tid >> 4;
    float acc[4][4];
#pragma unroll
    for (int a = 0; a < 4; a++)
#pragma unroll
        for (int c = 0; c < 4; c++) acc[a][c] = 0.f;
    for (int h = 0; h < 64; h++) {
        float4 a4 = *(const float4*)&piT[h][ig * 4];
        float4 b4 = *(const float4*)&pjT[h][jg * 4];
        float av[4] = { a4.x, a4.y, a4.z, a4.w };
        float bv[4] = { b4.x, b4.y, b4.z, b4.w };
#pragma unroll
        for (int a = 0; a < 4; a++)
#pragma unroll
            for (int c = 0; c < 4; c++) acc[a][c] += fabsf(av[a] - bv[c]);
    }
    float* dst = Ebuf + (size_t)tb * N_ * N_;
#pragma unroll
    for (int a = 0; a < 4; a++) {
        float4 o; o.x = __expf(-acc[a][0]); o.y = __expf(-acc[a][1]);
        o.z = __expf(-acc[a][2]); o.w = __expf(-acc[a][3]);
        *(float4*)&dst[(size_t)(i0 + ig * 4 + a) * N_ + j0 + jg * 4] = o;
    }
}

// ------------- inv[tb,j] = 1 / sum_i E[tb,i,j] -------------
__global__ void k_csum(const float* NF Ebuf, float* NF inv) {
    int tb = blockIdx.x, j = threadIdx.x;
    const float* e = Ebuf + (size_t)tb * N_ * N_;
    float S = 0.f;
    for (int i = 0; i < N_; i++) S += e[(size_t)i * N_ + j];
    inv[tb * N_ + j] = 1.f / S;
}

// ------------- A2[tb] = adj @ E[tb]  (64r x 256c tiles, padded SLT) -------------
__global__ __launch_bounds__(256) void k_a2(const float* NF adjm, const float* NF Ebuf, float* NF A2) {
    __shared__ float SLT[32][68];
    __shared__ float UL[32][256];
    int tid = threadIdx.x, cg = tid & 31, rg = tid >> 5;
    int rt = blockIdx.x, tb = blockIdx.y;     // grid (4, 96)
    const float* U = Ebuf + (size_t)tb * N_ * N_;
    float* dst = A2 + (size_t)tb * N_ * N_;
    int r0 = rt * 64;
    float acc[8][8];
#pragma unroll
    for (int r = 0; r < 8; r++)
#pragma unroll
        for (int c = 0; c < 8; c++) acc[r][c] = 0.f;
    for (int ch = 0; ch < 8; ++ch) {
        int m0 = ch * 32;
#pragma unroll
        for (int q = 0; q < 2; ++q) {
            int idx = q * 256 + tid; int mq = idx & 7, r = idx >> 3;
            float4 v = *(const float4*)&adjm[(size_t)(r0 + r) * N_ + m0 + mq * 4];
            SLT[mq * 4 + 0][r] = v.x; SLT[mq * 4 + 1][r] = v.y;
            SLT[mq * 4 + 2][r] = v.z; SLT[mq * 4 + 3][r] = v.w;
        }
#pragma unroll
        for (int q = 0; q < 8; ++q) {
            int i4 = q * 256 + tid; int c4 = i4 & 63, mm = i4 >> 6;
            *(float4*)&UL[mm][c4 * 4] = *(const float4*)&U[(size_t)(m0 + mm) * N_ + c4 * 4];
        }
        __syncthreads();
        for (int mm = 0; mm < 32; ++mm) {
            float sv[8];
            { float4 a = *(const float4*)&SLT[mm][rg * 8];
              float4 b = *(const float4*)&SLT[mm][rg * 8 + 4];
              sv[0] = a.x; sv[1] = a.y; sv[2] = a.z; sv[3] = a.w;
              sv[4] = b.x; sv[5] = b.y; sv[6] = b.z; sv[7] = b.w; }
            float2 uv[4];
#pragma unroll
            for (int uu = 0; uu < 4; uu++) uv[uu] = *(const float2*)&UL[mm][cg * 2 + uu * 64];
#pragma unroll
            for (int r = 0; r < 8; r++) {
#pragma unroll
                for (int uu = 0; uu < 4; uu++) {
                    acc[r][uu * 2]     = fmaf(sv[r], uv[uu].x, acc[r][uu * 2]);
                    acc[r][uu * 2 + 1] = fmaf(sv[r], uv[uu].y, acc[r][uu * 2 + 1]);
                }
            }
        }
        __syncthreads();
    }
#pragma unroll
    for (int r = 0; r < 8; r++) {
        size_t rowoff = (size_t)(r0 + rg * 8 + r) * N_;
#pragma unroll
        for (int uu = 0; uu < 4; uu++) {
            float2 o; o.x = acc[r][uu * 2]; o.y = acc[r][uu * 2 + 1];
            *(float2*)&dst[rowoff + cg * 2 + uu * 64] = o;
        }
    }
}

// ------------- Y0X[((tb*2+k)*N+n)*2+c] = S_k @ (x*inv) -------------
__global__ void k_y0xa(const float* NF s0, const float* NF s1, const float* NF inv,
                       const float* NF x, float* NF y0x) {
    int tb = blockIdx.x, kk = blockIdx.y;
    int t = tb / B_, b = tb % B_;
    const float* S = (kk ? s1 : s0) + (size_t)tb * N_ * N_;
    __shared__ float xw[256][2];
    int n = threadIdx.x;
    { float iv = inv[tb * N_ + n];
      xw[n][0] = x[(((size_t)b * T_ + t) * N_ + n) * 2 + 0] * iv;
      xw[n][1] = x[(((size_t)b * T_ + t) * N_ + n) * 2 + 1] * iv; }
    __syncthreads();
    float a0 = 0.f, a1 = 0.f;
    for (int m = 0; m < N_; m++) {
        float s = S[(size_t)n * N_ + m];
        a0 = fmaf(s, xw[m][0], a0); a1 = fmaf(s, xw[m][1], a1);
    }
    y0x[(((size_t)tb * 2 + kk) * N_ + n) * 2 + 0] = a0;
    y0x[(((size_t)tb * 2 + kk) * N_ + n) * 2 + 1] = a1;
}

// ------------- Y1X[((tb*2+k)*N+n)*64+c] = S_k @ (inv*cur0_t) -------------
__global__ __launch_bounds__(256) void k_y1x(const float* NF Ebuf, const float* NF A2,
                                             const float* NF inv, const float* NF cur0,
                                             float* NF y1x) {
    int tb = blockIdx.x, kk = blockIdx.y, rt = blockIdx.z;   // (96, 2, 32)
    int t = tb >> 3, b = tb & 7;
    int n0 = rt * 8;
    const float* S = (kk ? A2 : Ebuf) + (size_t)tb * N_ * N_ + (size_t)n0 * N_;
    const float* U = cur0 + ((size_t)b * T_ + t) * N_ * H_;
    const float* iv = inv + tb * N_;
    __shared__ float US[32][64];
    __shared__ float SS[8][36];
    int tid = threadIdx.x, cg = tid & 31, nn = tid >> 5;
    float a0 = 0.f, a1 = 0.f;
    for (int mc = 0; mc < 8; ++mc) {
        int m0 = mc * 32;
#pragma unroll
        for (int q = 0; q < 2; ++q) {
            int idx = q * 256 + tid; int mm = idx >> 4, c4 = idx & 15;
            float4 v = *(const float4*)&U[(size_t)(m0 + mm) * 64 + c4 * 4];
            float ivv = iv[m0 + mm];
            v.x *= ivv; v.y *= ivv; v.z *= ivv; v.w *= ivv;
            *(float4*)&US[mm][c4 * 4] = v;
        }
        if (tid < 64) {
            int n8 = tid >> 3, mq = tid & 7;
            float4 v = *(const float4*)&S[(size_t)n8 * N_ + m0 + mq * 4];
            SS[n8][mq * 4 + 0] = v.x; SS[n8][mq * 4 + 1] = v.y;
            SS[n8][mq * 4 + 2] = v.z; SS[n8][mq * 4 + 3] = v.w;
        }
        __syncthreads();
#pragma unroll 8
        for (int mm = 0; mm < 32; ++mm) {
            float s = SS[nn][mm];
            a0 = fmaf(s, US[mm][cg * 2], a0);
            a1 = fmaf(s, US[mm][cg * 2 + 1], a1);
        }
        __syncthreads();
    }
    float* dst = &y1x[(((size_t)tb * 2 + kk) * N_ + n0 + nn) * 64 + cg * 2];
    dst[0] = a0; dst[1] = a1;
}

// ------------- sa init: u1sa = ist_l + pa[:,0] -------------
__global__ void k_init0(const float* NF ist_l, const float* NF pa, float* NF u1) {
    int idx = blockIdx.x * 256 + threadIdx.x;   // 131072
    int b = idx >> 14, rem = idx & 16383;
    u1[idx] = ist_l[idx] + pa[(size_t)b * T_ * 16384 + rem];
}

// ------------- FUSED step kernel: y(sa-part) + mm + GRU epilogue -------------
// grid (32 ng, 4 os), 256 thr. Block owns nodes n0=ng*8 .. +8 and o-slice.
template <int XC, int OTOT, int MODE>
__global__ __launch_bounds__(256) void k_step(
    const float* NF S0, const float* NF S1, const float* NF u_in,
    const float* NF invt, const float* NF YXt,
    const float* NF W, const float* NF Bb,
    float* NF u1sa, float* NF u2sa, float* NF rbuf,
    const float* NF pa, float* NF seqout, float* NF hidout, int t)
{
    constexpr int I_ = XC + 64;
    constexpr int J2 = 2 * I_;
    constexpr int OSZ = OTOT / 4;
    int ng = blockIdx.x, os = blockIdx.y;
    int n0 = ng * 8;
    int tid = threadIdx.x;

    __shared__ float ybl[2][8][8][65];   // 33.3 KB
    __shared__ float US[32][64];         // 8 KB
    __shared__ float SS[2][8][36];       // 2.3 KB

    // ---- phase Y ----
    int cg = tid & 31, nn = tid >> 5;
    for (int b = 0; b < 8; ++b) {
        const float* ub  = u_in + (size_t)b * 16384;
        const float* ivb = invt + b * N_;
        const float* e0  = S0 + (size_t)b * 65536 + (size_t)n0 * N_;
        const float* e1  = S1 + (size_t)b * 65536 + (size_t)n0 * N_;
        float a00 = 0.f, a01 = 0.f, a10 = 0.f, a11 = 0.f;
        for (int mc = 0; mc < 8; ++mc) {
            int m0 = mc * 32;
#pragma unroll
            for (int q = 0; q < 2; ++q) {
                int idx = q * 256 + tid; int mm = idx >> 4, c4 = idx & 15;
                float4 v = *(const float4*)&ub[(size_t)(m0 + mm) * 64 + c4 * 4];
                float iv = ivb[m0 + mm];
                v.x *= iv; v.y *= iv; v.z *= iv; v.w *= iv;
                *(float4*)&US[mm][c4 * 4] = v;
            }
            if (tid < 128) {
                int kn = tid >> 3, mq = tid & 7;
                int kk = kn >> 3, n8 = kn & 7;
                const float* Sp = (kk ? e1 : e0) + (size_t)n8 * N_ + m0 + mq * 4;
                float4 v = *(const float4*)Sp;
                SS[kk][n8][mq * 4 + 0] = v.x; SS[kk][n8][mq * 4 + 1] = v.y;
                SS[kk][n8][mq * 4 + 2] = v.z; SS[kk][n8][mq * 4 + 3] = v.w;
            }
            __syncthreads();
#pragma unroll 8
            for (int mm = 0; mm < 32; ++mm) {
                float s0 = SS[0][nn][mm], s1 = SS[1][nn][mm];
                float u0 = US[mm][cg * 2], u1v = US[mm][cg * 2 + 1];
                a00 = fmaf(s0, u0, a00); a01 = fmaf(s0, u1v, a01);
                a10 = fmaf(s1, u0, a10); a11 = fmaf(s1, u1v, a11);
            }
            __syncthreads();
        }
        ybl[0][b][nn][cg * 2] = a00; ybl[0][b][nn][cg * 2 + 1] = a01;
        ybl[1][b][nn][cg * 2] = a10; ybl[1][b][nn][cg * 2 + 1] = a11;
    }
    __syncthreads();

    // ---- phase MM ----
    int o_l, bb;
    if (OTOT == 128) { o_l = tid & 31; bb = tid >> 5; }
    else             { o_l = tid & 15; bb = tid >> 4; }
    int o_g = os * OSZ + o_l;
    if (bb < 8) {
        for (int np = 0; np < 2; ++np) {
            float acc[4];
            const float* Wp[4];
#pragma unroll
            for (int q = 0; q < 4; ++q) {
                int n = n0 + np * 4 + q;
                acc[q] = Bb[(size_t)n * OTOT + o_g];
                Wp[q] = W + ((size_t)n * J2) * OTOT + o_g;
            }
#pragma unroll
            for (int kk = 0; kk < 2; ++kk) {
                const float* yxb = YXt + ((size_t)bb * 2 + kk) * N_ * XC;
                int jb = kk * I_;
                for (int c = 0; c < XC; ++c) {
#pragma unroll
                    for (int q = 0; q < 4; ++q) {
                        float xv = yxb[(size_t)(n0 + np * 4 + q) * XC + c];
                        acc[q] = fmaf(xv, Wp[q][(size_t)(jb + c) * OTOT], acc[q]);
                    }
                }
                for (int c = 0; c < 64; ++c) {
#pragma unroll
                    for (int q = 0; q < 4; ++q) {
                        float xv = ybl[kk][bb][np * 4 + q][c];
                        acc[q] = fmaf(xv, Wp[q][(size_t)(jb + XC + c) * OTOT], acc[q]);
                    }
                }
            }
#pragma unroll
            for (int q = 0; q < 4; ++q) {
                int n = n0 + np * 4 + q;
                size_t bn = (size_t)bb * N_ + n;
                if (MODE == 0) {
                    float v = 1.f / (1.f + __expf(-acc[q]));
                    if (o_g < 64) u2sa[bn * 64 + o_g] = v * u1sa[bn * 64 + o_g];   // z*sa
                    else          rbuf[bn * 64 + (o_g - 64)] = v;                  // r
                } else {
                    float hc = tanhf(acc[q]);
                    float r = rbuf[bn * 64 + o_g];
                    float s = u1sa[bn * 64 + o_g];
                    float ns = hc + r * (s - hc);
                    seqout[(((size_t)bb * T_ + t) * N_ + n) * 64 + o_g] = ns;
                    if (t < T_ - 1) u1sa[bn * 64 + o_g] = ns + pa[(((size_t)bb * T_ + (t + 1)) * N_ + n) * 64 + o_g];
                    else            hidout[bn * 64 + o_g] = ns;
                }
            }
        }
    }
}

extern "C" void kernel_launch(void* const* d_in, const int* in_sizes, int n_in,
                              void* d_out, int out_size, void* d_ws, size_t ws_size,
                              hipStream_t stream) {
    const float* x   = (const float*)d_in[0];
    const float* ist = (const float*)d_in[1];
    const float* ne  = (const float*)d_in[2];
    const float* pa  = (const float*)d_in[3];
    const float* gw0 = (const float*)d_in[4];
    const float* gb0 = (const float*)d_in[5];
    const float* uw0 = (const float*)d_in[6];
    const float* ub0 = (const float*)d_in[7];
    const float* gw1 = (const float*)d_in[8];
    const float* gb1 = (const float*)d_in[9];
    const float* uw1 = (const float*)d_in[10];
    const float* ub1 = (const float*)d_in[11];
    float* out = (float*)d_out;
    char*  base = (char*)d_ws;

    size_t off = 0;
    auto carve = [&](size_t bytes) { char* p = base + off; off += (bytes + 255) & ~(size_t)255; return p; };
    float* adjw = (float*)carve(65536ull * 4);
    float* Ebuf = (float*)carve(6291456ull * 4);
    float* inv  = (float*)carve(24576ull * 4);
    float* Wg   = (float*)carve(8388608ull * 4);    // shared l0 (132x128) / l1 (256x128)
    float* Wu   = (float*)carve(4194304ull * 4);    // shared l0 (132x64)  / l1 (256x64)
    float* Bg0  = (float*)carve(32768ull * 4);
    float* Bu0  = (float*)carve(16384ull * 4);
    float* Bg1  = (float*)carve(32768ull * 4);
    float* Bu1  = (float*)carve(16384ull * 4);
    float* u1sa = (float*)carve(131072ull * 4);
    float* u2sa = (float*)carve(131072ull * 4);
    float* rbuf = (float*)carve(131072ull * 4);
    float* y0x  = (float*)carve(98304ull * 4);
    float* y1x  = (float*)carve(3145728ull * 4);
    float* A2   = (float*)carve(6291456ull * 4);
    if (off > ws_size) { k_sentinel<<<1, 1, 0, stream>>>(out); return; }

    float* cur_out = out;                                   // (B,T,N,H)
    float* hid_out = out + (size_t)B_ * T_ * N_ * H_;       // (2,B,N,H)
    float* cur0    = cur_out;

    // ---- time-invariant precompute ----
    k_adj<<<256, 256, 0, stream>>>(ne, adjw);
    k_sub_t<<<dim3(16, 96), 256, 0, stream>>>(pa, Ebuf);
    k_csum<<<96, 256, 0, stream>>>(Ebuf, inv);
    k_a2<<<dim3(4, 96), 256, 0, stream>>>(adjw, Ebuf, A2);
    k_y0xa<<<dim3(96, 2), 256, 0, stream>>>(Ebuf, A2, inv, x, y0x);
    k_bias<128><<<256, 128, 0, stream>>>(ne, gb0, Bg0);
    k_bias<64><<<256, 64, 0, stream>>>(ne, ub0, Bu0);
    k_bias<128><<<256, 128, 0, stream>>>(ne, gb1, Bg1);
    k_bias<64><<<256, 64, 0, stream>>>(ne, ub1, Bu1);

    // ---- layer 0 ----
    {
        int t4g = N_ * 132 * 128 / 4, t4u = N_ * 132 * 64 / 4;
        k_wpool<<<(t4g + 255) / 256, 256, 0, stream>>>(ne, gw0, Wg, 132, 32, t4g);
        k_wpool<<<(t4u + 255) / 256, 256, 0, stream>>>(ne, uw0, Wu, 132, 16, t4u);
        k_init0<<<512, 256, 0, stream>>>(ist, pa, u1sa);
        for (int t = 0; t < T_; t++) {
            const float* Et   = Ebuf + (size_t)t * B_ * 65536;
            const float* A2t  = A2   + (size_t)t * B_ * 65536;
            const float* invt = inv  + (size_t)t * B_ * N_;
            const float* YXt  = y0x  + (size_t)t * B_ * 2 * N_ * 2;
            k_step<2, 128, 0><<<dim3(32, 4), 256, 0, stream>>>(
                Et, A2t, u1sa, invt, YXt, Wg, Bg0, u1sa, u2sa, rbuf, pa, nullptr, nullptr, t);
            k_step<2, 64, 1><<<dim3(32, 4), 256, 0, stream>>>(
                Et, A2t, u2sa, invt, YXt, Wu, Bu0, u1sa, u2sa, rbuf, pa, cur0, hid_out, t);
        }
    }
    // ---- layer 1 ----
    {
        int t4g = N_ * 256 * 128 / 4, t4u = N_ * 256 * 64 / 4;
        k_wpool<<<(t4g + 255) / 256, 256, 0, stream>>>(ne, gw1, Wg, 256, 32, t4g);
        k_wpool<<<(t4u + 255) / 256, 256, 0, stream>>>(ne, uw1, Wu, 256, 16, t4u);
        k_y1x<<<dim3(96, 2, 32), 256, 0, stream>>>(Ebuf, A2, inv, cur0, y1x);
        k_init0<<<512, 256, 0, stream>>>(ist + 131072, pa, u1sa);
        for (int t = 0; t < T_; t++) {
            const float* Et   = Ebuf + (size_t)t * B_ * 65536;
            const float* A2t  = A2   + (size_t)t * B_ * 65536;
            const float* invt = inv  + (size_t)t * B_ * N_;
            const float* YXt  = y1x  + (size_t)t * B_ * 2 * N_ * 64;
            k_step<64, 128, 0><<<dim3(32, 4), 256, 0, stream>>>(
                Et, A2t, u1sa, invt, YXt, Wg, Bg1, u1sa, u2sa, rbuf, pa, nullptr, nullptr, t);
            k_step<64, 64, 1><<<dim3(32, 4), 256, 0, stream>>>(
                Et, A2t, u2sa, invt, YXt, Wu, Bu1, u1sa, u2sa, rbuf, pa, cur_out, hid_out + 131072, t);
        }
    }
    (void)in_sizes; (void)n_in; (void)out_size;
}

// Round 10
// 1343.573 us; speedup vs baseline: 4.3175x; 4.3175x over previous
//
#include <hip/hip_runtime.h>
#include <math.h>

// AVWDCRNN round 10 (all-f32). r9 post-mortem: fused k_step was latency-starved
// (128 blocks, serial-b phase-Y with 128 barriers, 4x dup). Back to 4 launches
// per step with right-sized kernels:
//  k_y: 256 blocks, 35KB LDS, 4x4 reg tile, S non-transposed (broadcast reads).
//  k_mm: per-node block, W (n,j,o) lane-coalesced streams, xg in LDS, fused GRU.
// Precompute kernels identical to r9 (passed). ws 120.6 MB <= 122.5 proven (r7).

#define NF __restrict__
constexpr int N_ = 256, B_ = 8, T_ = 12, H_ = 64, E_ = 16;

__global__ void k_sentinel(float* NF out) { out[0] = 1.0e6f; }

// ---------------- adj = softmax(relu(ne ne^T), axis=1) ----------------
__global__ void k_adj(const float* NF ne, float* NF adj) {
    int n = blockIdx.x, m = threadIdx.x;
    __shared__ float en[E_];
    __shared__ float red[256];
    if (m < E_) en[m] = ne[n * E_ + m];
    __syncthreads();
    float s = 0.f;
#pragma unroll
    for (int d = 0; d < E_; d++) s += en[d] * ne[m * E_ + d];
    s = fmaxf(s, 0.f);
    red[m] = s; __syncthreads();
    for (int st = 128; st > 0; st >>= 1) { if (m < st) red[m] = fmaxf(red[m], red[m + st]); __syncthreads(); }
    float mx = red[0]; __syncthreads();
    float e = __expf(s - mx);
    red[m] = e; __syncthreads();
    for (int st = 128; st > 0; st >>= 1) { if (m < st) red[m] += red[m + st]; __syncthreads(); }
    adj[(size_t)n * N_ + m] = e / red[0];
}

// ------------- bias[n,o] = sum_d e[n,d] bp[d,o] -------------
template <int O>
__global__ void k_bias(const float* NF ne, const float* NF bp, float* NF Bout) {
    int n = blockIdx.x, o = threadIdx.x;
    float acc = 0.f;
#pragma unroll
    for (int d = 0; d < E_; d++) acc += ne[n * E_ + d] * bp[d * O + o];
    Bout[(size_t)n * O + o] = acc;
}

// ------------- W[n,j,o] = sum_d e[n,d] wp[d,j,o], float4 flat -------------
__global__ void k_wpool(const float* NF ne, const float* NF wp, float* NF W,
                        int I2, int O4, int total4) {
    int idx4 = blockIdx.x * 256 + threadIdx.x;
    if (idx4 >= total4) return;
    int o4 = idx4 % O4; int rem = idx4 / O4; int j = rem % I2; int n = rem / I2;
    const float* nrow = ne + n * E_;
    float ax = 0.f, ay = 0.f, az = 0.f, aw = 0.f;
#pragma unroll
    for (int d = 0; d < E_; d++) {
        float e = nrow[d];
        const float4 w = *(const float4*)&wp[(((size_t)d * I2 + j) * O4 + o4) * 4];
        ax = fmaf(e, w.x, ax); ay = fmaf(e, w.y, ay); az = fmaf(e, w.z, az); aw = fmaf(e, w.w, aw);
    }
    float4 r; r.x = ax; r.y = ay; r.z = az; r.w = aw;
    *(float4*)&W[(size_t)idx4 * 4] = r;
}

// ------------- E[tb,i,j] = exp(-L1(pa_i, pa_j)) ; tiled 64x64 -------------
__global__ __launch_bounds__(256) void k_sub_t(const float* NF pa, float* NF Ebuf) {
    int bx = blockIdx.x, tb = blockIdx.y;    // grid (16, 96)
    int it = bx & 3, jt = bx >> 2;
    int t = tb / B_, b = tb % B_;
    const float* p = pa + ((size_t)b * T_ + t) * N_ * H_;
    __shared__ float piT[64][64];
    __shared__ float pjT[64][64];
    int tid = threadIdx.x;
    int i0 = it * 64, j0 = jt * 64;
#pragma unroll
    for (int q = 0; q < 4; q++) {
        int idx = q * 256 + tid; int hq = idx & 15, i = idx >> 4;
        float4 v = *(const float4*)&p[(size_t)(i0 + i) * 64 + hq * 4];
        piT[hq * 4 + 0][i] = v.x; piT[hq * 4 + 1][i] = v.y; piT[hq * 4 + 2][i] = v.z; piT[hq * 4 + 3][i] = v.w;
        float4 w = *(const float4*)&p[(size_t)(j0 + i) * 64 + hq * 4];
        pjT[hq * 4 + 0][i] = w.x; pjT[hq * 4 + 1][i] = w.y; pjT[hq * 4 + 2][i] = w.z; pjT[hq * 4 + 3][i] = w.w;
    }
    __syncthreads();
    int jg = tid & 15, ig = tid >> 4;
    float acc[4][4];
#pragma unroll
    for (int a = 0; a < 4; a++)
#pragma unroll
        for (int c = 0; c < 4; c++) acc[a][c] = 0.f;
    for (int h = 0; h < 64; h++) {
        float4 a4 = *(const float4*)&piT[h][ig * 4];
        float4 b4 = *(const float4*)&pjT[h][jg * 4];
        float av[4] = { a4.x, a4.y, a4.z, a4.w };
        float bv[4] = { b4.x, b4.y, b4.z, b4.w };
#pragma unroll
        for (int a = 0; a < 4; a++)
#pragma unroll
            for (int c = 0; c < 4; c++) acc[a][c] += fabsf(av[a] - bv[c]);
    }
    float* dst = Ebuf + (size_t)tb * N_ * N_;
#pragma unroll
    for (int a = 0; a < 4; a++) {
        float4 o; o.x = __expf(-acc[a][0]); o.y = __expf(-acc[a][1]);
        o.z = __expf(-acc[a][2]); o.w = __expf(-acc[a][3]);
        *(float4*)&dst[(size_t)(i0 + ig * 4 + a) * N_ + j0 + jg * 4] = o;
    }
}

// ------------- inv[tb,j] = 1 / sum_i E[tb,i,j] -------------
__global__ void k_csum(const float* NF Ebuf, float* NF inv) {
    int tb = blockIdx.x, j = threadIdx.x;
    const float* e = Ebuf + (size_t)tb * N_ * N_;
    float S = 0.f;
    for (int i = 0; i < N_; i++) S += e[(size_t)i * N_ + j];
    inv[tb * N_ + j] = 1.f / S;
}

// ------------- A2[tb] = adj @ E[tb]  (64r x 256c tiles, padded SLT) -------------
__global__ __launch_bounds__(256) void k_a2(const float* NF adjm, const float* NF Ebuf, float* NF A2) {
    __shared__ float SLT[32][68];
    __shared__ float UL[32][256];
    int tid = threadIdx.x, cg = tid & 31, rg = tid >> 5;
    int rt = blockIdx.x, tb = blockIdx.y;     // grid (4, 96)
    const float* U = Ebuf + (size_t)tb * N_ * N_;
    float* dst = A2 + (size_t)tb * N_ * N_;
    int r0 = rt * 64;
    float acc[8][8];
#pragma unroll
    for (int r = 0; r < 8; r++)
#pragma unroll
        for (int c = 0; c < 8; c++) acc[r][c] = 0.f;
    for (int ch = 0; ch < 8; ++ch) {
        int m0 = ch * 32;
#pragma unroll
        for (int q = 0; q < 2; ++q) {
            int idx = q * 256 + tid; int mq = idx & 7, r = idx >> 3;
            float4 v = *(const float4*)&adjm[(size_t)(r0 + r) * N_ + m0 + mq * 4];
            SLT[mq * 4 + 0][r] = v.x; SLT[mq * 4 + 1][r] = v.y;
            SLT[mq * 4 + 2][r] = v.z; SLT[mq * 4 + 3][r] = v.w;
        }
#pragma unroll
        for (int q = 0; q < 8; ++q) {
            int i4 = q * 256 + tid; int c4 = i4 & 63, mm = i4 >> 6;
            *(float4*)&UL[mm][c4 * 4] = *(const float4*)&U[(size_t)(m0 + mm) * N_ + c4 * 4];
        }
        __syncthreads();
        for (int mm = 0; mm < 32; ++mm) {
            float sv[8];
            { float4 a = *(const float4*)&SLT[mm][rg * 8];
              float4 b = *(const float4*)&SLT[mm][rg * 8 + 4];
              sv[0] = a.x; sv[1] = a.y; sv[2] = a.z; sv[3] = a.w;
              sv[4] = b.x; sv[5] = b.y; sv[6] = b.z; sv[7] = b.w; }
            float2 uv[4];
#pragma unroll
            for (int uu = 0; uu < 4; uu++) uv[uu] = *(const float2*)&UL[mm][cg * 2 + uu * 64];
#pragma unroll
            for (int r = 0; r < 8; r++) {
#pragma unroll
                for (int uu = 0; uu < 4; uu++) {
                    acc[r][uu * 2]     = fmaf(sv[r], uv[uu].x, acc[r][uu * 2]);
                    acc[r][uu * 2 + 1] = fmaf(sv[r], uv[uu].y, acc[r][uu * 2 + 1]);
                }
            }
        }
        __syncthreads();
    }
#pragma unroll
    for (int r = 0; r < 8; r++) {
        size_t rowoff = (size_t)(r0 + rg * 8 + r) * N_;
#pragma unroll
        for (int uu = 0; uu < 4; uu++) {
            float2 o; o.x = acc[r][uu * 2]; o.y = acc[r][uu * 2 + 1];
            *(float2*)&dst[rowoff + cg * 2 + uu * 64] = o;
        }
    }
}

// ------------- Y0X[((tb*2+k)*N+n)*2+c] = S_k @ (x*inv) -------------
__global__ void k_y0xa(const float* NF s0, const float* NF s1, const float* NF inv,
                       const float* NF x, float* NF y0x) {
    int tb = blockIdx.x, kk = blockIdx.y;
    int t = tb / B_, b = tb % B_;
    const float* S = (kk ? s1 : s0) + (size_t)tb * N_ * N_;
    __shared__ float xw[256][2];
    int n = threadIdx.x;
    { float iv = inv[tb * N_ + n];
      xw[n][0] = x[(((size_t)b * T_ + t) * N_ + n) * 2 + 0] * iv;
      xw[n][1] = x[(((size_t)b * T_ + t) * N_ + n) * 2 + 1] * iv; }
    __syncthreads();
    float a0 = 0.f, a1 = 0.f;
    for (int m = 0; m < N_; m++) {
        float s = S[(size_t)n * N_ + m];
        a0 = fmaf(s, xw[m][0], a0); a1 = fmaf(s, xw[m][1], a1);
    }
    y0x[(((size_t)tb * 2 + kk) * N_ + n) * 2 + 0] = a0;
    y0x[(((size_t)tb * 2 + kk) * N_ + n) * 2 + 1] = a1;
}

// ------------- Y1X[((tb*2+k)*N+n)*64+c] = S_k @ (inv*cur0_t) -------------
__global__ __launch_bounds__(256) void k_y1x(const float* NF Ebuf, const float* NF A2,
                                             const float* NF inv, const float* NF cur0,
                                             float* NF y1x) {
    int tb = blockIdx.x, kk = blockIdx.y, rt = blockIdx.z;   // (96, 2, 32)
    int t = tb >> 3, b = tb & 7;
    int n0 = rt * 8;
    const float* S = (kk ? A2 : Ebuf) + (size_t)tb * N_ * N_ + (size_t)n0 * N_;
    const float* U = cur0 + ((size_t)b * T_ + t) * N_ * H_;
    const float* iv = inv + tb * N_;
    __shared__ float US[32][64];
    __shared__ float SS[8][36];
    int tid = threadIdx.x, cg = tid & 31, nn = tid >> 5;
    float a0 = 0.f, a1 = 0.f;
    for (int mc = 0; mc < 8; ++mc) {
        int m0 = mc * 32;
#pragma unroll
        for (int q = 0; q < 2; ++q) {
            int idx = q * 256 + tid; int mm = idx >> 4, c4 = idx & 15;
            float4 v = *(const float4*)&U[(size_t)(m0 + mm) * 64 + c4 * 4];
            float ivv = iv[m0 + mm];
            v.x *= ivv; v.y *= ivv; v.z *= ivv; v.w *= ivv;
            *(float4*)&US[mm][c4 * 4] = v;
        }
        if (tid < 64) {
            int n8 = tid >> 3, mq = tid & 7;
            float4 v = *(const float4*)&S[(size_t)n8 * N_ + m0 + mq * 4];
            SS[n8][mq * 4 + 0] = v.x; SS[n8][mq * 4 + 1] = v.y;
            SS[n8][mq * 4 + 2] = v.z; SS[n8][mq * 4 + 3] = v.w;
        }
        __syncthreads();
#pragma unroll 8
        for (int mm = 0; mm < 32; ++mm) {
            float s = SS[nn][mm];
            a0 = fmaf(s, US[mm][cg * 2], a0);
            a1 = fmaf(s, US[mm][cg * 2 + 1], a1);
        }
        __syncthreads();
    }
    float* dst = &y1x[(((size_t)tb * 2 + kk) * N_ + n0 + nn) * 64 + cg * 2];
    dst[0] = a0; dst[1] = a1;
}

// ------------- sa init: u1sa = ist_l + pa[:,0] -------------
__global__ void k_init0(const float* NF ist_l, const float* NF pa, float* NF u1) {
    int idx = blockIdx.x * 256 + threadIdx.x;   // 131072
    int b = idx >> 14, rem = idx & 16383;
    u1[idx] = ist_l[idx] + pa[(size_t)b * T_ * 16384 + rem];
}

// ------------- per-step y GEMM: ybuf[ms][b*2+k][n][c] = S_k[n,:] @ (inv.*u) -------
// grid (4 rt, 16 kb, 4 ms), 256 thr; 64 rows x 64 cols x 64-m slice per block.
__global__ __launch_bounds__(256) void k_y(const float* NF S0, const float* NF S1,
                                           const float* NF u_in, const float* NF invt,
                                           float* NF ybuf) {
    int rt = blockIdx.x, kb = blockIdx.y, ms = blockIdx.z;
    int b = kb >> 1, kk = kb & 1;
    const float* S  = (kk ? S1 : S0) + (size_t)b * 65536;
    const float* ub = u_in + (size_t)b * 16384;
    const float* iv = invt + b * N_;
    int r0 = rt * 64, m0 = ms * 64;
    __shared__ float SL[64][65];   // SL[r][m] non-transposed (conflict-free stores)
    __shared__ float UL[64][72];   // UL[m][c], float4-aligned rows
    int tid = threadIdx.x;
#pragma unroll
    for (int q = 0; q < 4; q++) {
        int idx = q * 256 + tid;
        int r = idx >> 4, mq = idx & 15;
        float4 v = *(const float4*)&S[(size_t)(r0 + r) * N_ + m0 + mq * 4];
        SL[r][mq * 4 + 0] = v.x; SL[r][mq * 4 + 1] = v.y;
        SL[r][mq * 4 + 2] = v.z; SL[r][mq * 4 + 3] = v.w;
        int mm = idx >> 4, cq = idx & 15;
        float4 u = *(const float4*)&ub[(size_t)(m0 + mm) * 64 + cq * 4];
        float ivv = iv[m0 + mm];
        u.x *= ivv; u.y *= ivv; u.z *= ivv; u.w *= ivv;
        *(float4*)&UL[mm][cq * 4] = u;
    }
    __syncthreads();
    int cg = tid & 15, rg = tid >> 4;
    float acc[4][4];
#pragma unroll
    for (int a = 0; a < 4; a++)
#pragma unroll
        for (int c = 0; c < 4; c++) acc[a][c] = 0.f;
    for (int mm = 0; mm < 64; ++mm) {
        float4 uv = *(const float4*)&UL[mm][cg * 4];
        float sv[4];
#pragma unroll
        for (int a = 0; a < 4; a++) sv[a] = SL[rg * 4 + a][mm];
#pragma unroll
        for (int a = 0; a < 4; a++) {
            acc[a][0] = fmaf(sv[a], uv.x, acc[a][0]);
            acc[a][1] = fmaf(sv[a], uv.y, acc[a][1]);
            acc[a][2] = fmaf(sv[a], uv.z, acc[a][2]);
            acc[a][3] = fmaf(sv[a], uv.w, acc[a][3]);
        }
    }
#pragma unroll
    for (int a = 0; a < 4; a++) {
        float4 o; o.x = acc[a][0]; o.y = acc[a][1]; o.z = acc[a][2]; o.w = acc[a][3];
        *(float4*)&ybuf[(((size_t)ms * 16 + kb) * N_ + r0 + rg * 4 + a) * 64 + cg * 4] = o;
    }
}

// ------------- per-node mm + fused GRU epilogue -------------
// grid 256 (n), 256 thr. xg[J2][12] in LDS; W (n,j,o) streamed lane-coalesced.
template <int I_, int OTOT, int MODE>
__global__ __launch_bounds__(256) void k_mm(
    const float* NF ybuf, const float* NF YXt, const float* NF W, const float* NF Bb,
    float* NF u1sa, float* NF u2sa, float* NF rbuf, const float* NF pa,
    float* NF seqout, float* NF hidout, int t)
{
    constexpr int XC = I_ - 64;
    constexpr int J2 = 2 * I_;
    constexpr int NG = 256 / OTOT;
    constexpr int BPG = 8 / NG;
    constexpr size_t SS = (size_t)16 * N_ * 64;   // ybuf slot stride
    int n = blockIdx.x, tid = threadIdx.x;
    __shared__ float xg[J2][12];
    // sa-part: sum 4 m-split slots
    {
        int b = tid >> 5, kk = (tid >> 4) & 1, c = (tid & 15) * 4;
        const float* yp = &ybuf[(((size_t)(b * 2 + kk)) * N_ + n) * 64 + c];
        float4 v = *(const float4*)yp;
        float4 v1 = *(const float4*)(yp + SS);
        float4 v2 = *(const float4*)(yp + 2 * SS);
        float4 v3 = *(const float4*)(yp + 3 * SS);
        v.x += v1.x + v2.x + v3.x; v.y += v1.y + v2.y + v3.y;
        v.z += v1.z + v2.z + v3.z; v.w += v1.w + v2.w + v3.w;
        int j = kk * I_ + XC + c;
        xg[j + 0][b] = v.x; xg[j + 1][b] = v.y; xg[j + 2][b] = v.z; xg[j + 3][b] = v.w;
    }
    // x-part
    if (XC == 64) {
        int b = tid >> 5, kk = (tid >> 4) & 1, c = (tid & 15) * 4;
        float4 v = *(const float4*)&YXt[(((size_t)(b * 2 + kk)) * N_ + n) * 64 + c];
        int j = kk * I_ + c;
        xg[j + 0][b] = v.x; xg[j + 1][b] = v.y; xg[j + 2][b] = v.z; xg[j + 3][b] = v.w;
    } else {
        if (tid < 32) {
            int b = tid >> 2, kk = (tid >> 1) & 1, c = tid & 1;
            xg[kk * I_ + c][b] = YXt[(((size_t)(b * 2 + kk)) * N_ + n) * 2 + c];
        }
    }
    __syncthreads();

    int o = tid % OTOT, bg = tid / OTOT;
    float acc[BPG];
    float bias = Bb[(size_t)n * OTOT + o];
#pragma unroll
    for (int q = 0; q < BPG; ++q) acc[q] = bias;
    const float* Wn = W + (size_t)n * J2 * OTOT + o;
#pragma unroll 4
    for (int j = 0; j < J2; ++j) {
        float w = Wn[(size_t)j * OTOT];
        if (BPG == 4) {
            float4 xv = *(const float4*)&xg[j][bg * 4];
            acc[0] = fmaf(xv.x, w, acc[0]); acc[1] = fmaf(xv.y, w, acc[1]);
            acc[2] = fmaf(xv.z, w, acc[2]); acc[3] = fmaf(xv.w, w, acc[3]);
        } else {
            float2 xv = *(const float2*)&xg[j][bg * 2];
            acc[0] = fmaf(xv.x, w, acc[0]); acc[1] = fmaf(xv.y, w, acc[1]);
        }
    }
#pragma unroll
    for (int q = 0; q < BPG; ++q) {
        int b = bg * BPG + q;
        size_t bn = (size_t)b * N_ + n;
        if (MODE == 0) {
            float v = 1.f / (1.f + __expf(-acc[q]));
            if (o < 64) u2sa[bn * 64 + o] = v * u1sa[bn * 64 + o];   // z*sa
            else        rbuf[bn * 64 + (o - 64)] = v;                // r
        } else {
            float hc = tanhf(acc[q]);
            float r = rbuf[bn * 64 + o];
            float s = u1sa[bn * 64 + o];
            float ns = hc + r * (s - hc);
            seqout[(((size_t)b * T_ + t) * N_ + n) * 64 + o] = ns;
            if (t < T_ - 1) u1sa[bn * 64 + o] = ns + pa[(((size_t)b * T_ + (t + 1)) * N_ + n) * 64 + o];
            else            hidout[bn * 64 + o] = ns;
        }
    }
}

extern "C" void kernel_launch(void* const* d_in, const int* in_sizes, int n_in,
                              void* d_out, int out_size, void* d_ws, size_t ws_size,
                              hipStream_t stream) {
    const float* x   = (const float*)d_in[0];
    const float* ist = (const float*)d_in[1];
    const float* ne  = (const float*)d_in[2];
    const float* pa  = (const float*)d_in[3];
    const float* gw0 = (const float*)d_in[4];
    const float* gb0 = (const float*)d_in[5];
    const float* uw0 = (const float*)d_in[6];
    const float* ub0 = (const float*)d_in[7];
    const float* gw1 = (const float*)d_in[8];
    const float* gb1 = (const float*)d_in[9];
    const float* uw1 = (const float*)d_in[10];
    const float* ub1 = (const float*)d_in[11];
    float* out = (float*)d_out;
    char*  base = (char*)d_ws;

    size_t off = 0;
    auto carve = [&](size_t bytes) { char* p = base + off; off += (bytes + 255) & ~(size_t)255; return p; };
    float* adjw = (float*)carve(65536ull * 4);
    float* Ebuf = (float*)carve(6291456ull * 4);
    float* inv  = (float*)carve(24576ull * 4);
    float* Wg   = (float*)carve(8388608ull * 4);    // shared l0 (132x128) / l1 (256x128)
    float* Wu   = (float*)carve(4194304ull * 4);    // shared l0 (132x64)  / l1 (256x64)
    float* Bg0  = (float*)carve(32768ull * 4);
    float* Bu0  = (float*)carve(16384ull * 4);
    float* Bg1  = (float*)carve(32768ull * 4);
    float* Bu1  = (float*)carve(16384ull * 4);
    float* u1sa = (float*)carve(131072ull * 4);
    float* u2sa = (float*)carve(131072ull * 4);
    float* rbuf = (float*)carve(131072ull * 4);
    float* y0x  = (float*)carve(98304ull * 4);
    float* y1x  = (float*)carve(3145728ull * 4);
    float* A2   = (float*)carve(6291456ull * 4);
    float* ybuf = (float*)carve((size_t)4 * 16 * 256 * 64 * 4);   // 4 MB
    if (off > ws_size) { k_sentinel<<<1, 1, 0, stream>>>(out); return; }

    float* cur_out = out;                                   // (B,T,N,H)
    float* hid_out = out + (size_t)B_ * T_ * N_ * H_;       // (2,B,N,H)
    float* cur0    = cur_out;

    // ---- time-invariant precompute ----
    k_adj<<<256, 256, 0, stream>>>(ne, adjw);
    k_sub_t<<<dim3(16, 96), 256, 0, stream>>>(pa, Ebuf);
    k_csum<<<96, 256, 0, stream>>>(Ebuf, inv);
    k_a2<<<dim3(4, 96), 256, 0, stream>>>(adjw, Ebuf, A2);
    k_y0xa<<<dim3(96, 2), 256, 0, stream>>>(Ebuf, A2, inv, x, y0x);
    k_bias<128><<<256, 128, 0, stream>>>(ne, gb0, Bg0);
    k_bias<64><<<256, 64, 0, stream>>>(ne, ub0, Bu0);
    k_bias<128><<<256, 128, 0, stream>>>(ne, gb1, Bg1);
    k_bias<64><<<256, 64, 0, stream>>>(ne, ub1, Bu1);

    // ---- layer 0 ----
    {
        int t4g = N_ * 132 * 128 / 4, t4u = N_ * 132 * 64 / 4;
        k_wpool<<<(t4g + 255) / 256, 256, 0, stream>>>(ne, gw0, Wg, 132, 32, t4g);
        k_wpool<<<(t4u + 255) / 256, 256, 0, stream>>>(ne, uw0, Wu, 132, 16, t4u);
        k_init0<<<512, 256, 0, stream>>>(ist, pa, u1sa);
        for (int t = 0; t < T_; t++) {
            const float* Et   = Ebuf + (size_t)t * B_ * 65536;
            const float* A2t  = A2   + (size_t)t * B_ * 65536;
            const float* invt = inv  + (size_t)t * B_ * N_;
            const float* YXt  = y0x  + (size_t)t * B_ * 2 * N_ * 2;
            k_y<<<dim3(4, 16, 4), 256, 0, stream>>>(Et, A2t, u1sa, invt, ybuf);
            k_mm<66, 128, 0><<<256, 256, 0, stream>>>(ybuf, YXt, Wg, Bg0, u1sa, u2sa, rbuf, pa, nullptr, nullptr, t);
            k_y<<<dim3(4, 16, 4), 256, 0, stream>>>(Et, A2t, u2sa, invt, ybuf);
            k_mm<66, 64, 1><<<256, 256, 0, stream>>>(ybuf, YXt, Wu, Bu0, u1sa, u2sa, rbuf, pa, cur0, hid_out, t);
        }
    }
    // ---- layer 1 ----
    {
        int t4g = N_ * 256 * 128 / 4, t4u = N_ * 256 * 64 / 4;
        k_wpool<<<(t4g + 255) / 256, 256, 0, stream>>>(ne, gw1, Wg, 256, 32, t4g);
        k_wpool<<<(t4u + 255) / 256, 256, 0, stream>>>(ne, uw1, Wu, 256, 16, t4u);
        k_y1x<<<dim3(96, 2, 32), 256, 0, stream>>>(Ebuf, A2, inv, cur0, y1x);
        k_init0<<<512, 256, 0, stream>>>(ist + 131072, pa, u1sa);
        for (int t = 0; t < T_; t++) {
            const float* Et   = Ebuf + (size_t)t * B_ * 65536;
            const float* A2t  = A2   + (size_t)t * B_ * 65536;
            const float* invt = inv  + (size_t)t * B_ * N_;
            const float* YXt  = y1x  + (size_t)t * B_ * 2 * N_ * 64;
            k_y<<<dim3(4, 16, 4), 256, 0, stream>>>(Et, A2t, u1sa, invt, ybuf);
            k_mm<128, 128, 0><<<256, 256, 0, stream>>>(ybuf, YXt, Wg, Bg1, u1sa, u2sa, rbuf, pa, nullptr, nullptr, t);
            k_y<<<dim3(4, 16, 4), 256, 0, stream>>>(Et, A2t, u2sa, invt, ybuf);
            k_mm<128, 64, 1><<<256, 256, 0, stream>>>(ybuf, YXt, Wu, Bu1, u1sa, u2sa, rbuf, pa, cur_out, hid_out + 131072, t);
        }
    }
    (void)in_sizes; (void)n_in; (void)out_size;
}